// Round 2
// baseline (238.369 us; speedup 1.0000x reference)
//
#include <hip/hip_runtime.h>
#include <hip/hip_bf16.h>

#define B_SZ 2
#define SEQ  2048
#define DM   1024
#define NH   16
#define HD   64

typedef __attribute__((ext_vector_type(8))) short bf16x8;
typedef __attribute__((ext_vector_type(4))) short bf16x4;
typedef __attribute__((ext_vector_type(4))) float f32x4;
typedef __attribute__((ext_vector_type(16))) float f32x16;

__device__ __forceinline__ short f2b(float f) {
    __hip_bfloat16 h = __float2bfloat16(f);
    return *reinterpret_cast<short*>(&h);
}

// pack two f32 -> one dword of 2 bf16 (lo=a, hi=b), RNE
__device__ __forceinline__ int cvtpk(float a, float b) {
    int r;
    asm("v_cvt_pk_bf16_f32 %0, %1, %2" : "=v"(r) : "v"(a), "v"(b));
    return r;
}

// async global->LDS, 16B per lane; LDS dest = wave-uniform base + lane*16 (m104)
__device__ __forceinline__ void async_copy16(void* lds, const void* g) {
    __builtin_amdgcn_global_load_lds(
        (const __attribute__((address_space(1))) void*)g,
        (__attribute__((address_space(3))) void*)lds, 16, 0, 0);
}

// ---------------------------------------------------------------------------
// Fused pre-pass: z<3 -> fp32->bf16 convert of q/k/v; z>=3 -> W transpose+cvt.
// ---------------------------------------------------------------------------
__global__ __launch_bounds__(256) void kPre(
    const float* __restrict__ q, const float* __restrict__ k, const float* __restrict__ v,
    const float* __restrict__ w0, const float* __restrict__ w1, const float* __restrict__ w2,
    short* __restrict__ qb, short* __restrict__ kb, short* __restrict__ vb,
    short* __restrict__ t0, short* __restrict__ t1, short* __restrict__ t2) {
    int z = blockIdx.z, tid = threadIdx.x;
    if (z < 3) {
        const float* src = z == 0 ? q : (z == 1 ? k : v);
        short*       dst = z == 0 ? qb : (z == 1 ? kb : vb);
        size_t i = ((size_t)blockIdx.x * 256 + tid) * 8;
        float4 a0 = *reinterpret_cast<const float4*>(src + i);
        float4 a1 = *reinterpret_cast<const float4*>(src + i + 4);
        bf16x8 c;
        c[0] = f2b(a0.x); c[1] = f2b(a0.y); c[2] = f2b(a0.z); c[3] = f2b(a0.w);
        c[4] = f2b(a1.x); c[5] = f2b(a1.y); c[6] = f2b(a1.z); c[7] = f2b(a1.w);
        *reinterpret_cast<bf16x8*>(dst + i) = c;
    } else {
        if (blockIdx.x >= 256) return;
        const float* w = z == 3 ? w0 : (z == 4 ? w1 : w2);
        short*       t = z == 3 ? t0 : (z == 4 ? t1 : t2);
        __shared__ float tile[64][65];
        int n0 = (blockIdx.x & 15) * 64, k0 = (blockIdx.x >> 4) * 64;
        int c = tid & 63, rr = tid >> 6;
#pragma unroll
        for (int i = 0; i < 16; i++) {
            int kk = i * 4 + rr;
            tile[kk][c] = w[(size_t)(k0 + kk) * DM + n0 + c];
        }
        __syncthreads();
#pragma unroll
        for (int i = 0; i < 16; i++) {
            int nn = i * 4 + rr;
            t[(size_t)(n0 + nn) * DM + k0 + c] = f2b(tile[c][nn]);
        }
    }
}

// ---------------------------------------------------------------------------
// Projection GEMM, m97 structure (unchanged this round).
// z = 0:Q 1:K (natural [seq][1024] out), 2:V (transposed [b][h][d][seq] out).
// ---------------------------------------------------------------------------
__global__ __launch_bounds__(256) void kProj(
    const short* __restrict__ qb, const short* __restrict__ kb, const short* __restrict__ vb,
    const short* __restrict__ wtq, const short* __restrict__ wtk, const short* __restrict__ wtv,
    short* __restrict__ qw, short* __restrict__ kw, short* __restrict__ vwT) {
    int z = blockIdx.z;
    const short* A  = z == 0 ? qb : (z == 1 ? kb : vb);
    const short* Bt = z == 0 ? wtq : (z == 1 ? wtk : wtv);

    __shared__ short As[128 * 64];
    __shared__ short Bs[128 * 64];

    int tid = threadIdx.x;
    int m0 = blockIdx.y * 128, n0 = blockIdx.x * 128;
    int wv = tid >> 6, lane = tid & 63, quad = lane >> 4, ln = lane & 15;
    int rblk = (wv >> 1) * 64, cblk = (wv & 1) * 64;

    int rA = wv * 32;
    int srow = rA + (lane >> 3), scol = (lane & 7) * 8;

    f32x4 zero = {0.f, 0.f, 0.f, 0.f};
    f32x4 acc[4][4];
#pragma unroll
    for (int rt = 0; rt < 4; rt++)
#pragma unroll
        for (int ct = 0; ct < 4; ct++) acc[rt][ct] = zero;

    for (int ks = 0; ks < DM; ks += 64) {
        const short* gA = A  + (size_t)(m0 + srow) * DM + ks + scol;
        const short* gB = Bt + (size_t)(n0 + srow) * DM + ks + scol;
#pragma unroll
        for (int i = 0; i < 4; i++) {
            async_copy16(&As[(rA + i * 8) * 64], gA + (size_t)i * 8 * DM);
            async_copy16(&Bs[(rA + i * 8) * 64], gB + (size_t)i * 8 * DM);
        }
        __syncthreads();
#pragma unroll
        for (int kc = 0; kc < 2; kc++) {
            bf16x8 af[4], bfv[4];
#pragma unroll
            for (int rt = 0; rt < 4; rt++)
                af[rt] = *reinterpret_cast<bf16x8*>(&As[(rblk + rt * 16 + ln) * 64 + kc * 32 + quad * 8]);
#pragma unroll
            for (int ct = 0; ct < 4; ct++)
                bfv[ct] = *reinterpret_cast<bf16x8*>(&Bs[(cblk + ct * 16 + ln) * 64 + kc * 32 + quad * 8]);
#pragma unroll
            for (int rt = 0; rt < 4; rt++)
#pragma unroll
                for (int ct = 0; ct < 4; ct++)
                    acc[rt][ct] = __builtin_amdgcn_mfma_f32_16x16x32_bf16(
                        af[rt], bfv[ct], acc[rt][ct], 0, 0, 0);
        }
        __syncthreads();
    }

    if (z < 2) {
        short* C = z == 0 ? qw : kw;
#pragma unroll
        for (int rt = 0; rt < 4; rt++)
#pragma unroll
            for (int r = 0; r < 4; r++) {
                int row = m0 + rblk + rt * 16 + quad * 4 + r;
#pragma unroll
                for (int ct = 0; ct < 4; ct++)
                    C[(size_t)row * DM + n0 + cblk + ct * 16 + ln] = f2b(acc[rt][ct][r]);
            }
    } else {
#pragma unroll
        for (int rt = 0; rt < 4; rt++) {
            int srow0 = m0 + rblk + rt * 16 + quad * 4;
            int bb = srow0 >> 11, lk = srow0 & (SEQ - 1);
#pragma unroll
            for (int ct = 0; ct < 4; ct++) {
                int coln = n0 + cblk + ct * 16 + ln;
                int hh = coln >> 6, dd = coln & 63;
                bf16x4 pk;
                pk[0] = f2b(acc[rt][ct][0]); pk[1] = f2b(acc[rt][ct][1]);
                pk[2] = f2b(acc[rt][ct][2]); pk[3] = f2b(acc[rt][ct][3]);
                *reinterpret_cast<bf16x4*>(
                    &vwT[(((size_t)bb * NH + hh) * HD + dd) * SEQ + lk]) = pk;
            }
        }
    }
}

// ---------------------------------------------------------------------------
// Flash attention v6: in-register P via cvt_pk + __shfl_xor(.,32) + per-half
// select (v5's permlane32_swap replaced — its return/swap convention was the
// one unverified piece and the v5 failure signature (absmax ~0.1, wrong P<->V
// association with correct row sums) matches a j-order permutation inside the
// B fragment; shfl_xor semantics are proven in this kernel since v4).
// LDS 70656 -> 35840 B (occupancy 2 -> 3 blocks/CU).
// 32x32 C/D layout (m74/m101): col=lane&31, row=(reg&3)+8*(reg>>2)+4*(lane>>5)
//   => reg r of lk-tile lt holds lk = lt*32 + 8*(r>>2) + 4*half + (r&3).
// PV B-operand, k-step s of tile lt: lane(l5,half) needs P[l5][lt*32 + s*16
// + 8*half + j], j=0..7.  With wX = cvtpk word of (p[2i],p[2i+1]) and
// xX = shfl_xor(wX,32):
//   step0 frag = half0: {wA,wB,xA,xB}=lk 0..7 | half1: {xC,xD,wC,wD}=lk 8..15
//   step1 frag = half0: {wE,wF,xE,xF}=lk16..23| half1: {xG,xH,wG,wH}=lk24..31
// ---------------------------------------------------------------------------
__global__ __launch_bounds__(256, 3) void kAttn(
    const short* __restrict__ qw, const short* __restrict__ kw, const short* __restrict__ vwT,
    const float* __restrict__ vmask, const float* __restrict__ qmask, float* __restrict__ out) {
    int b = blockIdx.z, h = blockIdx.y, lq0 = blockIdx.x * 128;
    int tid = threadIdx.x, wv = tid >> 6, lane = tid & 63;
    int l5 = lane & 31, half = lane >> 5;

    __shared__ short Ks[128][72];     // K chunk, [lk][d]   (stride 144B: conflict-free b128 reads)
    __shared__ short Vt[64][136];     // V chunk, [d][lk]   (stride 272B: conflict-free b128 reads)

    // Q fragments (B-operand 32x32x16: n=l5=lq, k=half*8+j per 16-k step), loop-invariant
    const short* qrow = qw + (size_t)(b * SEQ + lq0 + wv * 32 + l5) * DM + h * HD;
    bf16x8 qf[4];
#pragma unroll
    for (int ki = 0; ki < 4; ki++)
        qf[ki] = *reinterpret_cast<const bf16x8*>(qrow + ki * 16 + half * 8);

    float lrow = 0.f;
    f32x16 o0, o1;
#pragma unroll
    for (int i = 0; i < 16; i++) { o0[i] = 0.f; o1[i] = 0.f; }

    // staging (256 threads): K 128x64 (32B/thr), V 64x128 (32B/thr)
    int krow = tid >> 1, kcol = (tid & 1) * 32;
    int vrow = tid >> 2, vcol = (tid & 3) * 32;
    const short* kp = kw + (size_t)(b * SEQ + krow) * DM + h * HD + kcol;
    const short* vp = vwT + ((size_t)(b * NH + h) * HD + vrow) * SEQ + vcol;
    const float* vmb = vmask + b * SEQ;

    const float C1 = 0.18033688011f;   // 0.125 * log2(e)
    const float C2 = 1.4426950e10f;    // 1e10 * log2(e)

    bf16x8 kr[4], vr[4];
#pragma unroll
    for (int i = 0; i < 4; i++) {
        kr[i] = *reinterpret_cast<const bf16x8*>(kp + i * 8);
        vr[i] = *reinterpret_cast<const bf16x8*>(vp + i * 8);
    }

    for (int it = 0; it < SEQ / 128; it++) {
        int lk0 = it * 128;
        // ---- commit prefetched regs to LDS ----
#pragma unroll
        for (int i = 0; i < 4; i++) {
            *reinterpret_cast<bf16x8*>(&Ks[krow][kcol + i * 8]) = kr[i];
            *reinterpret_cast<bf16x8*>(&Vt[vrow][vcol + i * 8]) = vr[i];
        }
        __syncthreads();

        // ---- issue next chunk's global loads (overlap with compute) ----
        if (it + 1 < SEQ / 128) {
            kp += (size_t)128 * DM;
            vp += 128;
#pragma unroll
            for (int i = 0; i < 4; i++) {
                kr[i] = *reinterpret_cast<const bf16x8*>(kp + i * 8);
                vr[i] = *reinterpret_cast<const bf16x8*>(vp + i * 8);
            }
        }

        float rs = 0.f;
#pragma unroll
        for (int lt = 0; lt < 4; lt++) {
            // ---- S^T tile = K Q^T (32x32, d=64 in 4 k-steps) ----
            f32x16 s;
#pragma unroll
            for (int i = 0; i < 16; i++) s[i] = 0.f;
#pragma unroll
            for (int ki = 0; ki < 4; ki++) {
                bf16x8 kf = *reinterpret_cast<bf16x8*>(&Ks[lt * 32 + l5][ki * 16 + half * 8]);
                s = __builtin_amdgcn_mfma_f32_32x32x16_bf16(kf, qf[ki], s, 0, 0, 0);
            }

            // ---- scale+mask+exp2+rowsum (p = 2^(s*C1 + (m-1)*C2)) ----
            float p[16];
#pragma unroll
            for (int g = 0; g < 4; g++) {
                float4 mv = *reinterpret_cast<const float4*>(
                    &vmb[lk0 + lt * 32 + 8 * g + 4 * half]);
                float p0 = __builtin_amdgcn_exp2f(fmaf(s[4 * g + 0], C1, fmaf(mv.x, C2, -C2)));
                float p1 = __builtin_amdgcn_exp2f(fmaf(s[4 * g + 1], C1, fmaf(mv.y, C2, -C2)));
                float p2 = __builtin_amdgcn_exp2f(fmaf(s[4 * g + 2], C1, fmaf(mv.z, C2, -C2)));
                float p3 = __builtin_amdgcn_exp2f(fmaf(s[4 * g + 3], C1, fmaf(mv.w, C2, -C2)));
                rs += (p0 + p1) + (p2 + p3);
                p[4 * g + 0] = p0; p[4 * g + 1] = p1;
                p[4 * g + 2] = p2; p[4 * g + 3] = p3;
            }

            // ---- in-register P^T fragments: cvt_pk + shfl_xor(32) + select ----
            int wA = cvtpk(p[0],  p[1]),  wB = cvtpk(p[2],  p[3]);
            int wC = cvtpk(p[4],  p[5]),  wD = cvtpk(p[6],  p[7]);
            int wE = cvtpk(p[8],  p[9]),  wF = cvtpk(p[10], p[11]);
            int wG = cvtpk(p[12], p[13]), wH = cvtpk(p[14], p[15]);
            int xA = __shfl_xor(wA, 32), xB = __shfl_xor(wB, 32);
            int xC = __shfl_xor(wC, 32), xD = __shfl_xor(wD, 32);
            int xE = __shfl_xor(wE, 32), xF = __shfl_xor(wF, 32);
            int xG = __shfl_xor(wG, 32), xH = __shfl_xor(wH, 32);
            bool lo = (half == 0);
            union { int i[4]; bf16x8 v; } uA, uB;
            uA.i[0] = lo ? wA : xC; uA.i[1] = lo ? wB : xD;
            uA.i[2] = lo ? xA : wC; uA.i[3] = lo ? xB : wD;
            uB.i[0] = lo ? wE : xG; uB.i[1] = lo ? wF : xH;
            uB.i[2] = lo ? xE : wG; uB.i[3] = lo ? xF : wH;

            // ---- O^T += V^T P^T for this tile's two 16-k steps ----
            bf16x8 vf00 = *reinterpret_cast<bf16x8*>(&Vt[l5]     [(2 * lt) * 16 + half * 8]);
            bf16x8 vf01 = *reinterpret_cast<bf16x8*>(&Vt[32 + l5][(2 * lt) * 16 + half * 8]);
            bf16x8 vf10 = *reinterpret_cast<bf16x8*>(&Vt[l5]     [(2 * lt + 1) * 16 + half * 8]);
            bf16x8 vf11 = *reinterpret_cast<bf16x8*>(&Vt[32 + l5][(2 * lt + 1) * 16 + half * 8]);
            o0 = __builtin_amdgcn_mfma_f32_32x32x16_bf16(vf00, uA.v, o0, 0, 0, 0);
            o1 = __builtin_amdgcn_mfma_f32_32x32x16_bf16(vf01, uA.v, o1, 0, 0, 0);
            o0 = __builtin_amdgcn_mfma_f32_32x32x16_bf16(vf10, uB.v, o0, 0, 0, 0);
            o1 = __builtin_amdgcn_mfma_f32_32x32x16_bf16(vf11, uB.v, o1, 0, 0, 0);
        }

        rs += __shfl_xor(rs, 32);   // other half holds the complementary lk rows
        lrow += rs;
        __syncthreads();
    }

    // ---- epilogue: normalize + q_mask; C-layout rows are d -> float4 stores ----
    int lq = lq0 + wv * 32 + l5;
    float sc2 = (1.0f / lrow) * qmask[b * SEQ + lq];
    float* orow = out + (size_t)(b * SEQ + lq) * DM + h * HD;
#pragma unroll
    for (int g = 0; g < 4; g++) {
        float4 st0, st1;
        st0.x = o0[4 * g + 0] * sc2; st0.y = o0[4 * g + 1] * sc2;
        st0.z = o0[4 * g + 2] * sc2; st0.w = o0[4 * g + 3] * sc2;
        st1.x = o1[4 * g + 0] * sc2; st1.y = o1[4 * g + 1] * sc2;
        st1.z = o1[4 * g + 2] * sc2; st1.w = o1[4 * g + 3] * sc2;
        *reinterpret_cast<float4*>(&orow[8 * g + 4 * half]) = st0;
        *reinterpret_cast<float4*>(&orow[32 + 8 * g + 4 * half]) = st1;
    }
}

// ---------------------------------------------------------------------------
extern "C" void kernel_launch(void* const* d_in, const int* in_sizes, int n_in,
                              void* d_out, int out_size, void* d_ws, size_t ws_size,
                              hipStream_t stream) {
    const float* q  = (const float*)d_in[0];
    const float* k  = (const float*)d_in[1];
    const float* v  = (const float*)d_in[2];
    const float* vm = (const float*)d_in[3];
    const float* qm = (const float*)d_in[4];
    const float* qk = (const float*)d_in[5];
    const float* kk = (const float*)d_in[6];
    const float* vk = (const float*)d_in[7];
    float* out = (float*)d_out;

    short* ws  = (short*)d_ws;
    short* wtq = ws;
    short* wtk = wtq + 1024 * 1024;
    short* wtv = wtk + 1024 * 1024;
    short* vb  = wtv + 1024 * 1024;
    short* qw  = vb + (size_t)4096 * 1024;
    short* kw  = qw + (size_t)4096 * 1024;
    short* vwT = kw + (size_t)4096 * 1024;
    short* qb = (short*)d_out;
    short* kb = qb + (size_t)4096 * 1024;

    kPre <<<dim3(2048, 1, 6), 256, 0, stream>>>(q, k, v, qk, kk, vk,
                                                qb, kb, vb, wtq, wtk, wtv);
    kProj<<<dim3(8, 32, 3), 256, 0, stream>>>(qb, kb, vb, wtq, wtk, wtv, qw, kw, vwT);
    kAttn<<<dim3(16, 16, 2), 256, 0, stream>>>(qw, kw, vwT, vm, qm, out);
}

// Round 3
// 230.418 us; speedup vs baseline: 1.0345x; 1.0345x over previous
//
#include <hip/hip_runtime.h>
#include <hip/hip_bf16.h>

#define B_SZ 2
#define SEQ  2048
#define DM   1024
#define NH   16
#define HD   64

typedef __attribute__((ext_vector_type(8))) short bf16x8;
typedef __attribute__((ext_vector_type(4))) short bf16x4;
typedef __attribute__((ext_vector_type(4))) float f32x4;
typedef __attribute__((ext_vector_type(16))) float f32x16;

__device__ __forceinline__ short f2b(float f) {
    __hip_bfloat16 h = __float2bfloat16(f);
    return *reinterpret_cast<short*>(&h);
}

// pack two f32 -> one dword of 2 bf16 (lo=a, hi=b), RNE
__device__ __forceinline__ int cvtpk(float a, float b) {
    int r;
    asm("v_cvt_pk_bf16_f32 %0, %1, %2" : "=v"(r) : "v"(a), "v"(b));
    return r;
}

// async global->LDS, 16B per lane; LDS dest = wave-uniform base + lane*16 (m104)
__device__ __forceinline__ void async_copy16(void* lds, const void* g) {
    __builtin_amdgcn_global_load_lds(
        (const __attribute__((address_space(1))) void*)g,
        (__attribute__((address_space(3))) void*)lds, 16, 0, 0);
}

// ---------------------------------------------------------------------------
// Fused pre-pass: z<3 -> fp32->bf16 convert of q/k/v; z>=3 -> W transpose+cvt.
// ---------------------------------------------------------------------------
__global__ __launch_bounds__(256) void kPre(
    const float* __restrict__ q, const float* __restrict__ k, const float* __restrict__ v,
    const float* __restrict__ w0, const float* __restrict__ w1, const float* __restrict__ w2,
    short* __restrict__ qb, short* __restrict__ kb, short* __restrict__ vb,
    short* __restrict__ t0, short* __restrict__ t1, short* __restrict__ t2) {
    int z = blockIdx.z, tid = threadIdx.x;
    if (z < 3) {
        const float* src = z == 0 ? q : (z == 1 ? k : v);
        short*       dst = z == 0 ? qb : (z == 1 ? kb : vb);
        size_t i = ((size_t)blockIdx.x * 256 + tid) * 8;
        float4 a0 = *reinterpret_cast<const float4*>(src + i);
        float4 a1 = *reinterpret_cast<const float4*>(src + i + 4);
        bf16x8 c;
        c[0] = f2b(a0.x); c[1] = f2b(a0.y); c[2] = f2b(a0.z); c[3] = f2b(a0.w);
        c[4] = f2b(a1.x); c[5] = f2b(a1.y); c[6] = f2b(a1.z); c[7] = f2b(a1.w);
        *reinterpret_cast<bf16x8*>(dst + i) = c;
    } else {
        if (blockIdx.x >= 256) return;
        const float* w = z == 3 ? w0 : (z == 4 ? w1 : w2);
        short*       t = z == 3 ? t0 : (z == 4 ? t1 : t2);
        __shared__ float tile[64][65];
        int n0 = (blockIdx.x & 15) * 64, k0 = (blockIdx.x >> 4) * 64;
        int c = tid & 63, rr = tid >> 6;
#pragma unroll
        for (int i = 0; i < 16; i++) {
            int kk = i * 4 + rr;
            tile[kk][c] = w[(size_t)(k0 + kk) * DM + n0 + c];
        }
        __syncthreads();
#pragma unroll
        for (int i = 0; i < 16; i++) {
            int nn = i * 4 + rr;
            t[(size_t)(n0 + nn) * DM + k0 + c] = f2b(tile[c][nn]);
        }
    }
}

// ---------------------------------------------------------------------------
// Projection GEMM, m97 structure (unchanged this round).
// z = 0:Q 1:K (natural [seq][1024] out), 2:V (transposed [b][h][d][seq] out).
// ---------------------------------------------------------------------------
__global__ __launch_bounds__(256) void kProj(
    const short* __restrict__ qb, const short* __restrict__ kb, const short* __restrict__ vb,
    const short* __restrict__ wtq, const short* __restrict__ wtk, const short* __restrict__ wtv,
    short* __restrict__ qw, short* __restrict__ kw, short* __restrict__ vwT) {
    int z = blockIdx.z;
    const short* A  = z == 0 ? qb : (z == 1 ? kb : vb);
    const short* Bt = z == 0 ? wtq : (z == 1 ? wtk : wtv);

    __shared__ short As[128 * 64];
    __shared__ short Bs[128 * 64];

    int tid = threadIdx.x;
    int m0 = blockIdx.y * 128, n0 = blockIdx.x * 128;
    int wv = tid >> 6, lane = tid & 63, quad = lane >> 4, ln = lane & 15;
    int rblk = (wv >> 1) * 64, cblk = (wv & 1) * 64;

    int rA = wv * 32;
    int srow = rA + (lane >> 3), scol = (lane & 7) * 8;

    f32x4 zero = {0.f, 0.f, 0.f, 0.f};
    f32x4 acc[4][4];
#pragma unroll
    for (int rt = 0; rt < 4; rt++)
#pragma unroll
        for (int ct = 0; ct < 4; ct++) acc[rt][ct] = zero;

    for (int ks = 0; ks < DM; ks += 64) {
        const short* gA = A  + (size_t)(m0 + srow) * DM + ks + scol;
        const short* gB = Bt + (size_t)(n0 + srow) * DM + ks + scol;
#pragma unroll
        for (int i = 0; i < 4; i++) {
            async_copy16(&As[(rA + i * 8) * 64], gA + (size_t)i * 8 * DM);
            async_copy16(&Bs[(rA + i * 8) * 64], gB + (size_t)i * 8 * DM);
        }
        __syncthreads();
#pragma unroll
        for (int kc = 0; kc < 2; kc++) {
            bf16x8 af[4], bfv[4];
#pragma unroll
            for (int rt = 0; rt < 4; rt++)
                af[rt] = *reinterpret_cast<bf16x8*>(&As[(rblk + rt * 16 + ln) * 64 + kc * 32 + quad * 8]);
#pragma unroll
            for (int ct = 0; ct < 4; ct++)
                bfv[ct] = *reinterpret_cast<bf16x8*>(&Bs[(cblk + ct * 16 + ln) * 64 + kc * 32 + quad * 8]);
#pragma unroll
            for (int rt = 0; rt < 4; rt++)
#pragma unroll
                for (int ct = 0; ct < 4; ct++)
                    acc[rt][ct] = __builtin_amdgcn_mfma_f32_16x16x32_bf16(
                        af[rt], bfv[ct], acc[rt][ct], 0, 0, 0);
        }
        __syncthreads();
    }

    if (z < 2) {
        short* C = z == 0 ? qw : kw;
#pragma unroll
        for (int rt = 0; rt < 4; rt++)
#pragma unroll
            for (int r = 0; r < 4; r++) {
                int row = m0 + rblk + rt * 16 + quad * 4 + r;
#pragma unroll
                for (int ct = 0; ct < 4; ct++)
                    C[(size_t)row * DM + n0 + cblk + ct * 16 + ln] = f2b(acc[rt][ct][r]);
            }
    } else {
#pragma unroll
        for (int rt = 0; rt < 4; rt++) {
            int srow0 = m0 + rblk + rt * 16 + quad * 4;
            int bb = srow0 >> 11, lk = srow0 & (SEQ - 1);
#pragma unroll
            for (int ct = 0; ct < 4; ct++) {
                int coln = n0 + cblk + ct * 16 + ln;
                int hh = coln >> 6, dd = coln & 63;
                bf16x4 pk;
                pk[0] = f2b(acc[rt][ct][0]); pk[1] = f2b(acc[rt][ct][1]);
                pk[2] = f2b(acc[rt][ct][2]); pk[3] = f2b(acc[rt][ct][3]);
                *reinterpret_cast<bf16x4*>(
                    &vwT[(((size_t)bb * NH + hh) * HD + dd) * SEQ + lk]) = pk;
            }
        }
    }
}

// ---------------------------------------------------------------------------
// Flash attention v7: fixes the v6 post-mortem finding — the 512-block grid
// capped residency at 2 blocks/CU (8 waves/CU), leaving the kernel
// latency-bound regardless of LDS/VGPR headroom.  Now: lq tile 64 per block,
// 4 waves as a 2x2 (g = lq group, h2 = 64-key half of each 128-key chunk)
// decomposition -> grid 32x16x2 = 1024 blocks = 4 blocks/CU = 16 waves/CU.
// Staging, chunk size, LDS (35840 B), and all fragment math identical to v6;
// each wave runs lk tiles LT = h2*2+lt, lt in {0,1}.  Without a running max,
// O and rowsum partials over lk combine by pure addition: one 16 KB LDS
// exchange (overlaid on Ks, lane-major = conflict-free) after the loop.
// 32x32 C/D layout (m74/m101): col=lane&31, row=(reg&3)+8*(reg>>2)+4*(lane>>5)
//   => reg r of lk-tile LT holds lk = LT*32 + 8*(r>>2) + 4*half + (r&3).
// In-register P (proven in v6): cvt_pk pairs + __shfl_xor(32) + per-half
// select build the PV B-fragments without an LDS round trip.
// ---------------------------------------------------------------------------
__global__ __launch_bounds__(256, 4) void kAttn(
    const short* __restrict__ qw, const short* __restrict__ kw, const short* __restrict__ vwT,
    const float* __restrict__ vmask, const float* __restrict__ qmask, float* __restrict__ out) {
    int b = blockIdx.z, h = blockIdx.y, lq0 = blockIdx.x * 64;
    int tid = threadIdx.x, wv = tid >> 6, lane = tid & 63;
    int l5 = lane & 31, half = lane >> 5;
    int g = wv & 1, h2 = wv >> 1;

    __shared__ short Ks[128][72];     // K chunk, [lk][d]   (stride 144B: conflict-free b128 reads)
    __shared__ short Vt[64][136];     // V chunk, [d][lk]   (stride 272B: conflict-free b128 reads)

    // Q fragments (B-operand 32x32x16: n=l5=lq, k=half*8+j per 16-k step), loop-invariant
    const short* qrow = qw + (size_t)(b * SEQ + lq0 + g * 32 + l5) * DM + h * HD;
    bf16x8 qf[4];
#pragma unroll
    for (int ki = 0; ki < 4; ki++)
        qf[ki] = *reinterpret_cast<const bf16x8*>(qrow + ki * 16 + half * 8);

    float lrow = 0.f;
    f32x16 o0, o1;
#pragma unroll
    for (int i = 0; i < 16; i++) { o0[i] = 0.f; o1[i] = 0.f; }

    // staging (256 threads): K 128x64 (32B/thr), V 64x128 (32B/thr)
    int krow = tid >> 1, kcol = (tid & 1) * 32;
    int vrow = tid >> 2, vcol = (tid & 3) * 32;
    const short* kp = kw + (size_t)(b * SEQ + krow) * DM + h * HD + kcol;
    const short* vp = vwT + ((size_t)(b * NH + h) * HD + vrow) * SEQ + vcol;
    const float* vmb = vmask + b * SEQ;

    const float C1 = 0.18033688011f;   // 0.125 * log2(e)
    const float C2 = 1.4426950e10f;    // 1e10 * log2(e)

    bf16x8 kr[4], vr[4];
#pragma unroll
    for (int i = 0; i < 4; i++) {
        kr[i] = *reinterpret_cast<const bf16x8*>(kp + i * 8);
        vr[i] = *reinterpret_cast<const bf16x8*>(vp + i * 8);
    }

    for (int it = 0; it < SEQ / 128; it++) {
        int lk0 = it * 128;
        // ---- commit prefetched regs to LDS ----
#pragma unroll
        for (int i = 0; i < 4; i++) {
            *reinterpret_cast<bf16x8*>(&Ks[krow][kcol + i * 8]) = kr[i];
            *reinterpret_cast<bf16x8*>(&Vt[vrow][vcol + i * 8]) = vr[i];
        }
        __syncthreads();

        // ---- issue next chunk's global loads (overlap with compute) ----
        if (it + 1 < SEQ / 128) {
            kp += (size_t)128 * DM;
            vp += 128;
#pragma unroll
            for (int i = 0; i < 4; i++) {
                kr[i] = *reinterpret_cast<const bf16x8*>(kp + i * 8);
                vr[i] = *reinterpret_cast<const bf16x8*>(vp + i * 8);
            }
        }

        float rs = 0.f;
#pragma unroll
        for (int lt = 0; lt < 2; lt++) {
            int LT = h2 * 2 + lt;           // this wave's lk tile within the chunk
            // ---- S^T tile = K Q^T (32x32, d=64 in 4 k-steps) ----
            f32x16 s;
#pragma unroll
            for (int i = 0; i < 16; i++) s[i] = 0.f;
#pragma unroll
            for (int ki = 0; ki < 4; ki++) {
                bf16x8 kf = *reinterpret_cast<bf16x8*>(&Ks[LT * 32 + l5][ki * 16 + half * 8]);
                s = __builtin_amdgcn_mfma_f32_32x32x16_bf16(kf, qf[ki], s, 0, 0, 0);
            }

            // ---- scale+mask+exp2+rowsum (p = 2^(s*C1 + (m-1)*C2)) ----
            float p[16];
#pragma unroll
            for (int g4 = 0; g4 < 4; g4++) {
                float4 mv = *reinterpret_cast<const float4*>(
                    &vmb[lk0 + LT * 32 + 8 * g4 + 4 * half]);
                float p0 = __builtin_amdgcn_exp2f(fmaf(s[4 * g4 + 0], C1, fmaf(mv.x, C2, -C2)));
                float p1 = __builtin_amdgcn_exp2f(fmaf(s[4 * g4 + 1], C1, fmaf(mv.y, C2, -C2)));
                float p2 = __builtin_amdgcn_exp2f(fmaf(s[4 * g4 + 2], C1, fmaf(mv.z, C2, -C2)));
                float p3 = __builtin_amdgcn_exp2f(fmaf(s[4 * g4 + 3], C1, fmaf(mv.w, C2, -C2)));
                rs += (p0 + p1) + (p2 + p3);
                p[4 * g4 + 0] = p0; p[4 * g4 + 1] = p1;
                p[4 * g4 + 2] = p2; p[4 * g4 + 3] = p3;
            }

            // ---- in-register P^T fragments: cvt_pk + shfl_xor(32) + select ----
            int wA = cvtpk(p[0],  p[1]),  wB = cvtpk(p[2],  p[3]);
            int wC = cvtpk(p[4],  p[5]),  wD = cvtpk(p[6],  p[7]);
            int wE = cvtpk(p[8],  p[9]),  wF = cvtpk(p[10], p[11]);
            int wG = cvtpk(p[12], p[13]), wH = cvtpk(p[14], p[15]);
            int xA = __shfl_xor(wA, 32), xB = __shfl_xor(wB, 32);
            int xC = __shfl_xor(wC, 32), xD = __shfl_xor(wD, 32);
            int xE = __shfl_xor(wE, 32), xF = __shfl_xor(wF, 32);
            int xG = __shfl_xor(wG, 32), xH = __shfl_xor(wH, 32);
            bool lo = (half == 0);
            union { int i[4]; bf16x8 v; } uA, uB;
            uA.i[0] = lo ? wA : xC; uA.i[1] = lo ? wB : xD;
            uA.i[2] = lo ? xA : wC; uA.i[3] = lo ? xB : wD;
            uB.i[0] = lo ? wE : xG; uB.i[1] = lo ? wF : xH;
            uB.i[2] = lo ? xE : wG; uB.i[3] = lo ? xF : wH;

            // ---- O^T += V^T P^T for this tile's two 16-k steps ----
            bf16x8 vf00 = *reinterpret_cast<bf16x8*>(&Vt[l5]     [(2 * LT) * 16 + half * 8]);
            bf16x8 vf01 = *reinterpret_cast<bf16x8*>(&Vt[32 + l5][(2 * LT) * 16 + half * 8]);
            bf16x8 vf10 = *reinterpret_cast<bf16x8*>(&Vt[l5]     [(2 * LT + 1) * 16 + half * 8]);
            bf16x8 vf11 = *reinterpret_cast<bf16x8*>(&Vt[32 + l5][(2 * LT + 1) * 16 + half * 8]);
            o0 = __builtin_amdgcn_mfma_f32_32x32x16_bf16(vf00, uA.v, o0, 0, 0, 0);
            o1 = __builtin_amdgcn_mfma_f32_32x32x16_bf16(vf01, uA.v, o1, 0, 0, 0);
            o0 = __builtin_amdgcn_mfma_f32_32x32x16_bf16(vf10, uB.v, o0, 0, 0, 0);
            o1 = __builtin_amdgcn_mfma_f32_32x32x16_bf16(vf11, uB.v, o1, 0, 0, 0);
        }

        rs += __shfl_xor(rs, 32);   // other half holds the complementary lk rows
        lrow += rs;
        __syncthreads();
    }

    // ---- cross-wave combine: h2=1 partials -> LDS (lane-major, conflict-free),
    //      h2=0 waves add, normalize, store.  Safe to overlay Ks/Vt: all waves
    //      are past the loop's final __syncthreads(). ----
    float* cb = reinterpret_cast<float*>(&Ks[0][0]);   // 128 rows x 32 vals, lane-major: 16 KB
    float* lr = reinterpret_cast<float*>(&Vt[0][0]);   // 128 floats
    int ci = g * 64 + lane;
    if (h2 == 1) {
#pragma unroll
        for (int i = 0; i < 16; i++) cb[ci + 128 * i]        = o0[i];
#pragma unroll
        for (int i = 0; i < 16; i++) cb[ci + 128 * (16 + i)] = o1[i];
        lr[ci] = lrow;
    }
    __syncthreads();
    if (h2 == 1) return;
#pragma unroll
    for (int i = 0; i < 16; i++) o0[i] += cb[ci + 128 * i];
#pragma unroll
    for (int i = 0; i < 16; i++) o1[i] += cb[ci + 128 * (16 + i)];
    lrow += lr[ci];

    // ---- epilogue: normalize + q_mask; C-layout rows are d -> float4 stores ----
    int lq = lq0 + g * 32 + l5;
    float sc2 = (1.0f / lrow) * qmask[b * SEQ + lq];
    float* orow = out + (size_t)(b * SEQ + lq) * DM + h * HD;
#pragma unroll
    for (int g4 = 0; g4 < 4; g4++) {
        float4 st0, st1;
        st0.x = o0[4 * g4 + 0] * sc2; st0.y = o0[4 * g4 + 1] * sc2;
        st0.z = o0[4 * g4 + 2] * sc2; st0.w = o0[4 * g4 + 3] * sc2;
        st1.x = o1[4 * g4 + 0] * sc2; st1.y = o1[4 * g4 + 1] * sc2;
        st1.z = o1[4 * g4 + 2] * sc2; st1.w = o1[4 * g4 + 3] * sc2;
        *reinterpret_cast<float4*>(&orow[8 * g4 + 4 * half]) = st0;
        *reinterpret_cast<float4*>(&orow[32 + 8 * g4 + 4 * half]) = st1;
    }
}

// ---------------------------------------------------------------------------
extern "C" void kernel_launch(void* const* d_in, const int* in_sizes, int n_in,
                              void* d_out, int out_size, void* d_ws, size_t ws_size,
                              hipStream_t stream) {
    const float* q  = (const float*)d_in[0];
    const float* k  = (const float*)d_in[1];
    const float* v  = (const float*)d_in[2];
    const float* vm = (const float*)d_in[3];
    const float* qm = (const float*)d_in[4];
    const float* qk = (const float*)d_in[5];
    const float* kk = (const float*)d_in[6];
    const float* vk = (const float*)d_in[7];
    float* out = (float*)d_out;

    short* ws  = (short*)d_ws;
    short* wtq = ws;
    short* wtk = wtq + 1024 * 1024;
    short* wtv = wtk + 1024 * 1024;
    short* vb  = wtv + 1024 * 1024;
    short* qw  = vb + (size_t)4096 * 1024;
    short* kw  = qw + (size_t)4096 * 1024;
    short* vwT = kw + (size_t)4096 * 1024;
    short* qb = (short*)d_out;
    short* kb = qb + (size_t)4096 * 1024;

    kPre <<<dim3(2048, 1, 6), 256, 0, stream>>>(q, k, v, qk, kk, vk,
                                                qb, kb, vb, wtq, wtk, wtv);
    kProj<<<dim3(8, 32, 3), 256, 0, stream>>>(qb, kb, vb, wtq, wtk, wtv, qw, kw, vwT);
    kAttn<<<dim3(32, 16, 2), 256, 0, stream>>>(qw, kw, vwT, vm, qm, out);
}